// Round 4
// baseline (3143.985 us; speedup 1.0000x reference)
//
#include <hip/hip_runtime.h>
#include <cstdint>
#include <cstddef>

#define B_ 64
#define T_ 2048
#define I_ 256
#define H_ 256
#define G_ 768   // 3*H

typedef _Float16 h2v __attribute__((ext_vector_type(2)));
typedef _Float16 v8h __attribute__((ext_vector_type(8)));
typedef float    v4f __attribute__((ext_vector_type(4)));
typedef uint32_t u32x4 __attribute__((ext_vector_type(4)));

union U32h { uint32_t u; h2v h; };

// ---------------------------------------------------------------------------
// prep: Whh fp32 [768][256] -> MFMA A-fragment layout (16x16x32 f16).
// Fragment (rt, kb), rt in [0,48), kb in [0,8):
//   lane l element e holds A[row][k] with row = rt*16 + (l&15),
//   k = kb*32 + (l>>4)*8 + e   (e = 0..7, packed as 4 dwords of f16-pairs).
// Dword address: Wp[ ((rt*8 + kb)*64 + l)*4 + d ]  (d = e>>1).
// This mirrors gemm_gi's verified As-read pattern exactly.
// ---------------------------------------------------------------------------
__global__ void prep_whh_frag(const float* __restrict__ Whh, uint32_t* __restrict__ Wp) {
    int rt = blockIdx.x;           // 0..47
    int kb = blockIdx.y;           // 0..7
    int lane = threadIdx.x;        // 0..63
    int r16 = lane & 15, hi2 = lane >> 4;
    const float* src = Whh + (size_t)(rt * 16 + r16) * 256 + kb * 32 + hi2 * 8;
    uint32_t d[4];
    for (int p = 0; p < 4; ++p) {
        U32h u; u.h = h2v{(_Float16)src[2 * p], (_Float16)src[2 * p + 1]};
        d[p] = u.u;
    }
    *(u32x4*)(Wp + (((size_t)rt * 8 + kb) * 64 + lane) * 4) = u32x4{d[0], d[1], d[2], d[3]};
}

// ---------------------------------------------------------------------------
// gi GEMM (unchanged): gi[t_local*64 + b][n]
// ---------------------------------------------------------------------------
#define LDA 56
#define LDB 56

__launch_bounds__(256, 2)
__global__ void gemm_gi(const float* __restrict__ x, const float* __restrict__ Wih,
                        const float* __restrict__ bih, _Float16* __restrict__ gi,
                        int t0) {
    __shared__ __align__(16) _Float16 As[64 * LDA];
    __shared__ __align__(16) _Float16 Bs[384 * LDB];
    int tid  = threadIdx.x;
    int t    = t0 + blockIdx.x;
    int n0   = blockIdx.y * 384;
    int lane = tid & 63, wave = tid >> 6;
    int quad = lane >> 4, r16 = lane & 15;

    v4f acc[24];
#pragma unroll
    for (int i = 0; i < 24; ++i) acc[i] = v4f{0.f, 0.f, 0.f, 0.f};

    for (int ki = 0; ki < 8; ++ki) {
        int k0 = ki * 32;
        __syncthreads();
#pragma unroll
        for (int s = 0; s < 2; ++s) {
            int slot = tid + s * 256;
            int row = slot >> 3;
            int part = slot & 7;
            const float* xp = x + ((size_t)row * T_ + t) * I_ + k0 + part * 4;
            float4 v = *(const float4*)xp;
            U32h u0, u1;
            u0.h = h2v{(_Float16)v.x, (_Float16)v.y};
            u1.h = h2v{(_Float16)v.z, (_Float16)v.w};
            uint32_t* dst = (uint32_t*)&As[row * LDA + part * 4];
            dst[0] = u0.u; dst[1] = u1.u;
        }
#pragma unroll
        for (int s = 0; s < 12; ++s) {
            int slot = tid + s * 256;
            int row = slot >> 3;
            int part = slot & 7;
            const float* wp = Wih + (size_t)(n0 + row) * I_ + k0 + part * 4;
            float4 v = *(const float4*)wp;
            U32h u0, u1;
            u0.h = h2v{(_Float16)v.x, (_Float16)v.y};
            u1.h = h2v{(_Float16)v.z, (_Float16)v.w};
            uint32_t* dst = (uint32_t*)&Bs[row * LDB + part * 4];
            dst[0] = u0.u; dst[1] = u1.u;
        }
        __syncthreads();
        v8h af = *(const v8h*)&As[(wave * 16 + r16) * LDA + quad * 8];
#pragma unroll
        for (int nt = 0; nt < 24; ++nt) {
            v8h bf = *(const v8h*)&Bs[(nt * 16 + r16) * LDB + quad * 8];
            acc[nt] = __builtin_amdgcn_mfma_f32_16x16x32_f16(af, bf, acc[nt], 0, 0, 0);
        }
    }
#pragma unroll
    for (int nt = 0; nt < 24; ++nt) {
        int n = n0 + nt * 16 + r16;
        float bias = bih[n];
#pragma unroll
        for (int reg = 0; reg < 4; ++reg) {
            int m = wave * 16 + quad * 4 + reg;
            size_t off = ((size_t)blockIdx.x * 64 + m) * G_ + n;
            gi[off] = (_Float16)(acc[nt][reg] + bias);
        }
    }
}

// ---------------------------------------------------------------------------
// Recurrent kernel v6: MFMA GEMV with register-stationary weight fragments.
//
// WHY MFMA: v3-v5 proved the allocator reserves headroom for 2 workgroups/CU
// for VALU-consumed register arrays (116 VGPR @512thr, 64 @1024thr) and
// scratch-spills the weights; the per-step reload (384 KB/block at ~134
// B/cyc/CU L2/scratch BW) = the measured ~2830 cyc/step. MFMA operands can
// live in AGPRs (unified file) and be read directly by the matrix pipe, so
// the compiler has an on-chip home for 192 regs/lane of weights (precedent:
// m97 164V+64A, m214 249V at 512thr).
//
// Structure: one block (512 thr, 8 waves) per batch element. y[768] = Whh*h
// tiled as 48 row-tiles x 8 k-blocks of mfma_f32_16x16x32_f16. Wave w owns
// row-tiles w*6..w*6+5 (48 A-fragments, 192 dwords/lane). B-fragment = h
// broadcast into all 16 columns (every lane reads the same 16B of h from
// LDS -> broadcast, conflict-free; all 16 D-columns carry identical y).
// D layout (verified via gemm_gi): row=(lane>>4)*4+reg, col=lane&15.
// Lanes with (lane&15)==0 write y to LDS; 256 pointwise threads finish.
// ---------------------------------------------------------------------------
__global__ void __launch_bounds__(512, 1)
rec_step(const v8h* __restrict__ Wfrag, const float* __restrict__ bhh,
         const _Float16* __restrict__ gi, const float* __restrict__ h_init,
         float* __restrict__ out, float* __restrict__ hN,
         float* __restrict__ h_carry, int t0, int len) {
    __shared__ __align__(16) _Float16 hb[2][256];
    __shared__ __align__(16) float ypart[G_];   // full dots (each wave owns full K)

    int b = blockIdx.x;
    int tid = threadIdx.x;
    int lane = tid & 63, wave = tid >> 6;
    int r16 = lane & 15, hi2 = lane >> 4;
    int j = tid & 255;   // pointwise column for tid < 256

    // ---- load 48 A-fragments (192 dwords/lane) ----
    v8h w[48];
#pragma unroll
    for (int f = 0; f < 48; ++f) {
        int rt = wave * 6 + (f >> 3);
        int kb = f & 7;
        w[f] = Wfrag[((size_t)rt * 8 + kb) * 64 + lane];
    }

    // ---- pointwise-thread state (tid < 256) ----
    float bh0 = 0.f, bh1 = 0.f, bh2 = 0.f, hprev = 0.f;
    float g0 = 0.f, g1 = 0.f, g2 = 0.f;
    const _Float16* gp = gi + (size_t)b * G_ + j;
    float* outp = out + (size_t)b * T_ * H_ + (size_t)t0 * H_ + j;
    if (tid < 256) {
        bh0 = bhh[j]; bh1 = bhh[256 + j]; bh2 = bhh[512 + j];
        hprev = h_init[b * 256 + j];
        hb[0][j] = (_Float16)hprev;
        g0 = (float)gp[0]; g1 = (float)gp[256]; g2 = (float)gp[512];
    }
    __syncthreads();

    int cur = 0;
    for (int t = 0; t < len; ++t) {
        // prefetch next step's gi (consumed after the dot phase)
        float p0 = 0.f, p1 = 0.f, p2 = 0.f;
        if (tid < 256 && t + 1 < len) {
            const _Float16* gq = gp + (size_t)(t + 1) * B_ * G_;
            p0 = (float)gq[0]; p1 = (float)gq[256]; p2 = (float)gq[512];
        }

        // ---- B-fragments: h broadcast (16-lane groups read same 16B) ----
        v8h bf[8];
#pragma unroll
        for (int kb = 0; kb < 8; ++kb)
            bf[kb] = *(const v8h*)&hb[cur][kb * 32 + hi2 * 8];

        // ---- MFMA: 6 row-tiles x 8 k-blocks per wave ----
#pragma unroll
        for (int r = 0; r < 6; ++r) {
            v4f acc = v4f{0.f, 0.f, 0.f, 0.f};
#pragma unroll
            for (int kb = 0; kb < 8; ++kb)
                acc = __builtin_amdgcn_mfma_f32_16x16x32_f16(w[r * 8 + kb], bf[kb], acc, 0, 0, 0);
            if (r16 == 0)
                *(v4f*)&ypart[(wave * 6 + r) * 16 + hi2 * 4] = acc;
        }
        __syncthreads();

        // ---- pointwise phase ----
        if (tid < 256) {
            float s0 = ypart[j]       + bh0;
            float s1 = ypart[256 + j] + bh1;
            float s2 = ypart[512 + j] + bh2;
            float r = 1.f / (1.f + __expf(-(g0 + s0)));
            float u = 1.f / (1.f + __expf(-(g2 + s2)));
            float carg = g1 + r * s1;
            carg = fminf(fmaxf(carg, -20.f), 20.f);
            float e2 = __expf(2.f * carg);
            float n = (e2 - 1.f) / (e2 + 1.f);
            float hnew = hprev + u * (n - hprev);
            outp[(size_t)t * H_] = hnew;
            hb[cur ^ 1][j] = (_Float16)hnew;
            hprev = hnew;
            g0 = p0; g1 = p1; g2 = p2;
        }
        __syncthreads();
        cur ^= 1;
    }
    if (tid < 256) {
        h_carry[b * 256 + j] = hprev;
        if (t0 + len == T_) hN[b * 256 + j] = hprev;
    }
}

// ---------------------------------------------------------------------------
extern "C" void kernel_launch(void* const* d_in, const int* in_sizes, int n_in,
                              void* d_out, int out_size, void* d_ws, size_t ws_size,
                              hipStream_t stream) {
    const float* x   = (const float*)d_in[0];
    const float* h0  = (const float*)d_in[1];
    const float* Wih = (const float*)d_in[2];
    const float* bih = (const float*)d_in[3];
    const float* Whh = (const float*)d_in[4];
    const float* bhh = (const float*)d_in[5];
    float* out = (float*)d_out;
    float* hN  = out + (size_t)B_ * T_ * H_;

    char* ws = (char*)d_ws;
    float*    h_carry = (float*)ws;                       // 65536 B
    uint32_t* Wprep   = (uint32_t*)(ws + 65536);          // 393216 B (48*8 frags * 64 lanes * 16B)
    _Float16* gi      = (_Float16*)(ws + 65536 + 393216);

    const size_t head = 65536 + 393216;
    const size_t per_t = (size_t)B_ * G_ * sizeof(_Float16);  // 98304 B
    size_t avail = (ws_size > head) ? (ws_size - head) : 0;
    int tc = (int)(avail / per_t);
    if (tc > T_) tc = T_;
    if (tc < 1)  tc = 1;
    int nch = (T_ + tc - 1) / tc;
    tc = (T_ + nch - 1) / nch;

    hipLaunchKernelGGL(prep_whh_frag, dim3(48, 8), dim3(64), 0, stream, Whh, Wprep);
    for (int t0 = 0; t0 < T_; t0 += tc) {
        int len = (T_ - t0 < tc) ? (T_ - t0) : tc;
        hipLaunchKernelGGL(gemm_gi, dim3(len, 2), dim3(256), 0, stream,
                           x, Wih, bih, gi, t0);
        const float* hi = (t0 == 0) ? h0 : h_carry;
        hipLaunchKernelGGL(rec_step, dim3(64), dim3(512), 0, stream,
                           (const v8h*)Wprep, bhh, gi, hi, out, hN, h_carry, t0, len);
    }
}